// Round 2
// baseline (399.921 us; speedup 1.0000x reference)
//
#include <hip/hip_runtime.h>

// ---------------------------------------------------------------------------
// MultiHeadAttention: B=2, S=2048, H=16, Dh=64, D=1024, causal mask, fp32 I/O.
// R2: barrier-free attention (K/V frags direct from global, wave-private P),
//     fused QKV GEMM (N=3072), register-prefetch double-buffered GEMMs.
// ---------------------------------------------------------------------------

#define B_   2
#define S_   2048
#define H_   16
#define DH_  64
#define D_   1024
#define M_   (B_ * S_)          // 4096 rows

typedef __attribute__((ext_vector_type(8))) short short8;
typedef __attribute__((ext_vector_type(4))) short short4_t;
typedef float v4f __attribute__((ext_vector_type(4)));

__device__ __forceinline__ short f2bf(float f) {
    union { float f; unsigned u; } v; v.f = f;
    unsigned r = v.u + 0x7fffu + ((v.u >> 16) & 1u);  // round-to-nearest-even
    return (short)(r >> 16);
}

// ---------------------------------------------------------------------------
// Kernel 1: cast X[4M] and Wq,Wk,Wv,Wo[1M each] fp32 -> bf16 (float4-vectorized)
// Wb layout: [Wq | Wk | Wv | Wo] contiguous -> rows 0..3071 usable as fused W.
// ---------------------------------------------------------------------------
__global__ __launch_bounds__(256) void cast_kernel(
    const float* __restrict__ X,
    const float* __restrict__ Wq, const float* __restrict__ Wk,
    const float* __restrict__ Wv, const float* __restrict__ Wo,
    short* __restrict__ Xb, short* __restrict__ Wb)
{
    const int NX4 = (M_ * D_) / 4;      // 1,048,576
    const int NW4 = (D_ * D_) / 4;      // 262,144
    int idx = blockIdx.x * 256 + threadIdx.x;   // grid: 2,097,152 total

    const float* src; short* dst; int off;
    if (idx < NX4) { src = X; dst = Xb; off = idx; }
    else {
        int r = idx - NX4;
        int sel = r >> 18;
        int o = r & (NW4 - 1);
        src = (sel == 0) ? Wq : (sel == 1) ? Wk : (sel == 2) ? Wv : Wo;
        dst = Wb + sel * (D_ * D_);
        off = o;
    }
    float4 f = ((const float4*)src)[off];
    short4_t s;
    s.x = f2bf(f.x); s.y = f2bf(f.y); s.z = f2bf(f.z); s.w = f2bf(f.w);
    *(short4_t*)(dst + (size_t)off * 4) = s;
}

// ---------------------------------------------------------------------------
// Kernel 2: C = A(bf16,[M,K]) @ W(bf16,[N,K])^T + bias.  BM=128, BK=64.
// Register-prefetch double buffering: next k-tile's global loads issue while
// MFMAs consume the current LDS tile.
// MODE 0 (BN=128): fused QKV epilogue. N=3072; n0 block-uniform selects Q/K/V.
//   Q,K -> bf16 [bh][s][64];  V -> bf16 [bh][64][s] (transposed).
// MODE 2 (BN=64): fp32 out, [M,1024] (final projection).
// ---------------------------------------------------------------------------
template<int BN, int MODE>
__global__ __launch_bounds__(256) void gemm_kernel(
    const short* __restrict__ A, const short* __restrict__ W,
    const float* __restrict__ bq, const float* __restrict__ bk,
    const float* __restrict__ bv, void* __restrict__ out,
    int M, int N, int K)
{
    __shared__ __align__(16) short As[128][72];
    __shared__ __align__(16) short Bs[BN][72];

    const int t    = threadIdx.x;
    const int lane = t & 63;
    const int wave = t >> 6;
    const int m0 = blockIdx.y * 128;
    const int n0 = blockIdx.x * BN;

    // wave tiling: BN=128 -> 2x2 waves of 64x64; BN=64 -> 2x2 waves of 64x32
    const int wm = (wave >> 1) * 64;
    const int wn = (wave & 1) * (BN / 2);
    const int NJ = BN / 32;            // acc cols per wave (4 or 2)
    const int BIT = BN / 32;           // B staging iters (4 or 2)

    v4f acc[4][4] = {};                // use [4][NJ]

    const int lrow = t >> 3;           // 0..31
    const int lcol = (t & 7) * 8;

    const short* Ap = A + (size_t)(m0 + lrow) * K + lcol;
    const short* Wp = W + (size_t)(n0 + lrow) * K + lcol;

    uint4 pa[4], pb[4];
    #pragma unroll
    for (int it = 0; it < 4; ++it) pa[it] = *(const uint4*)(Ap + (size_t)it * 32 * K);
    #pragma unroll
    for (int it = 0; it < BIT; ++it) pb[it] = *(const uint4*)(Wp + (size_t)it * 32 * K);

    for (int k0 = 0; k0 < K; k0 += 64) {
        __syncthreads();
        #pragma unroll
        for (int it = 0; it < 4; ++it) *(uint4*)&As[lrow + it * 32][lcol] = pa[it];
        #pragma unroll
        for (int it = 0; it < BIT; ++it) *(uint4*)&Bs[lrow + it * 32][lcol] = pb[it];

        if (k0 + 64 < K) {   // issue next tile's loads before the barrier
            #pragma unroll
            for (int it = 0; it < 4; ++it)
                pa[it] = *(const uint4*)(Ap + (k0 + 64) + (size_t)it * 32 * K);
            #pragma unroll
            for (int it = 0; it < BIT; ++it)
                pb[it] = *(const uint4*)(Wp + (k0 + 64) + (size_t)it * 32 * K);
        }
        __syncthreads();

        #pragma unroll
        for (int kk = 0; kk < 2; ++kk) {
            const int fr = lane & 15;
            const int fo = kk * 32 + (lane >> 4) * 8;
            short8 af[4], bf[4];
            #pragma unroll
            for (int i = 0; i < 4; ++i) af[i] = *(const short8*)&As[wm + i * 16 + fr][fo];
            #pragma unroll
            for (int j = 0; j < NJ; ++j) bf[j] = *(const short8*)&Bs[wn + j * 16 + fr][fo];
            #pragma unroll
            for (int i = 0; i < 4; ++i)
                #pragma unroll
                for (int j = 0; j < NJ; ++j)
                    acc[i][j] = __builtin_amdgcn_mfma_f32_16x16x32_bf16(af[i], bf[j], acc[i][j], 0, 0, 0);
        }
    }

    // Epilogue.  C/D layout: col = lane&15, row = (lane>>4)*4 + r
    const int colb = n0 + wn + (lane & 15);
    const int rowb = m0 + wm + (lane >> 4) * 4;
    const int sel  = n0 >> 10;   // block-uniform for MODE 0 (1024 % 128 == 0)
    const float* bias = (MODE == 2) ? bq : (sel == 0) ? bq : (sel == 1) ? bk : bv;
    short* outQ = (short*)out;                       // MODE 0: Qh base
    short* outK = outQ + 4194304;
    short* outV = outK + 4194304;

    #pragma unroll
    for (int j = 0; j < NJ; ++j) {
        int col = colb + j * 16;
        float bv_ = bias[col & 1023];
        #pragma unroll
        for (int i = 0; i < 4; ++i) {
            #pragma unroll
            for (int r = 0; r < 4; ++r) {
                int row = rowb + i * 16 + r;
                float v = acc[i][j][r] + bv_;
                if (MODE == 2) {
                    ((float*)out)[(size_t)row * 1024 + col] = v;
                } else {
                    int c = col & 1023;
                    int b = row >> 11, s = row & 2047, h = c >> 6, d = c & 63;
                    int bh = (b << 4) + h;
                    if (sel == 0)
                        outQ[((size_t)bh * S_ + s) * DH_ + d] = f2bf(v);
                    else if (sel == 1)
                        outK[((size_t)bh * S_ + s) * DH_ + d] = f2bf(v);
                    else
                        outV[((size_t)bh << 17) + ((size_t)d << 11) + s] = f2bf(v);
                }
            }
        }
    }
}

// ---------------------------------------------------------------------------
// Kernel 3: causal flash attention — BARRIER-FREE.
// Each wave owns 32 q-rows (2 MFMA m-frags). K and V^T fragments are loaded
// directly from global (16B/lane contiguous); only the P C->A layout
// round-trip touches LDS, and it is wave-private (no __syncthreads anywhere).
// Grid: (16, 32 bh), 256 thr.  Wave p = 63 - (bx*4+w), rows 32p..32p+31.
// ---------------------------------------------------------------------------
__global__ __launch_bounds__(256, 2) void attn_kernel(
    const short* __restrict__ Q, const short* __restrict__ Kh,
    const short* __restrict__ Vt, short* __restrict__ ctx)
{
    __shared__ __align__(16) short Ps[4][2][16][72];   // [wave][mfrag][row][col]

    const int t    = threadIdx.x;
    const int lane = t & 63;
    const int w    = t >> 6;
    const int p    = 63 - (blockIdx.x * 4 + w);        // longest waves first
    const int bh   = blockIdx.y;
    const int qr0  = p * 32;
    const int ktmax = (qr0 + 31) >> 6;

    const int lm = lane & 15;          // fragment row/col selector
    const int lg = lane >> 4;          // 0..3

    const short* Qb = Q  + ((size_t)bh * S_) * DH_;
    const short* Kb = Kh + ((size_t)bh * S_) * DH_;
    const short* Vb = Vt + ((size_t)bh << 17);

    // Q fragments: A[m = lm][k = kk*32 + lg*8 + j]
    short8 qf[2][2];
    #pragma unroll
    for (int t2 = 0; t2 < 2; ++t2)
        #pragma unroll
        for (int kk = 0; kk < 2; ++kk)
            qf[t2][kk] = *(const short8*)(Qb + (size_t)(qr0 + t2 * 16 + lm) * DH_ + kk * 32 + lg * 8);

    float m_i[2][4], l_i[2][4];
    v4f o[2][4] = {};
    #pragma unroll
    for (int t2 = 0; t2 < 2; ++t2)
        #pragma unroll
        for (int r = 0; r < 4; ++r) { m_i[t2][r] = -1e30f; l_i[t2][r] = 0.f; }

    for (int kt = 0; kt <= ktmax; ++kt) {
        const int kv0 = kt * 64;

        // K frags: B[n = kv = lm][k = d] ; V frags: B[k = kv][n = d = lm]
        short8 kf[2][4], vf[2][4];
        #pragma unroll
        for (int kk = 0; kk < 2; ++kk)
            #pragma unroll
            for (int j = 0; j < 4; ++j) {
                kf[kk][j] = *(const short8*)(Kb + (size_t)(kv0 + j * 16 + lm) * DH_ + kk * 32 + lg * 8);
                vf[kk][j] = *(const short8*)(Vb + ((size_t)(j * 16 + lm) << 11) + kv0 + kk * 32 + lg * 8);
            }

        // S = Q K^T  (16 MFMAs, two independent m-frags)
        v4f sc[2][4] = {};
        #pragma unroll
        for (int kk = 0; kk < 2; ++kk)
            #pragma unroll
            for (int t2 = 0; t2 < 2; ++t2)
                #pragma unroll
                for (int j = 0; j < 4; ++j)
                    sc[t2][j] = __builtin_amdgcn_mfma_f32_16x16x32_bf16(qf[t2][kk], kf[kk][j], sc[t2][j], 0, 0, 0);

        // online softmax, both frags (C-layout: col=lm, row=lg*4+r)
        #pragma unroll
        for (int t2 = 0; t2 < 2; ++t2) {
            float rm[4];
            const int rowb = qr0 + t2 * 16 + lg * 4;
            #pragma unroll
            for (int r = 0; r < 4; ++r) rm[r] = -1e30f;
            if (kt == ktmax) {   // wave-uniform: apply causal mask
                #pragma unroll
                for (int j = 0; j < 4; ++j) {
                    int col = kv0 + j * 16 + lm;
                    #pragma unroll
                    for (int r = 0; r < 4; ++r) {
                        float v = sc[t2][j][r] * 0.125f;
                        if (col > rowb + r) v = -1e30f;
                        sc[t2][j][r] = v;
                        rm[r] = fmaxf(rm[r], v);
                    }
                }
            } else {
                #pragma unroll
                for (int j = 0; j < 4; ++j)
                    #pragma unroll
                    for (int r = 0; r < 4; ++r) {
                        float v = sc[t2][j][r] * 0.125f;
                        sc[t2][j][r] = v;
                        rm[r] = fmaxf(rm[r], v);
                    }
            }
            #pragma unroll
            for (int off = 1; off < 16; off <<= 1)
                #pragma unroll
                for (int r = 0; r < 4; ++r)
                    rm[r] = fmaxf(rm[r], __shfl_xor(rm[r], off, 64));

            float alpha[4], rs[4];
            #pragma unroll
            for (int r = 0; r < 4; ++r) {
                float mn = fmaxf(m_i[t2][r], rm[r]);
                alpha[r] = __expf(m_i[t2][r] - mn);
                m_i[t2][r] = mn;
                rs[r] = 0.f;
                #pragma unroll
                for (int j = 0; j < 4; ++j) {
                    float e = __expf(sc[t2][j][r] - mn);
                    sc[t2][j][r] = e;
                    rs[r] += e;
                }
            }
            #pragma unroll
            for (int off = 1; off < 16; off <<= 1)
                #pragma unroll
                for (int r = 0; r < 4; ++r)
                    rs[r] += __shfl_xor(rs[r], off, 64);
            #pragma unroll
            for (int r = 0; r < 4; ++r) l_i[t2][r] = l_i[t2][r] * alpha[r] + rs[r];
            #pragma unroll
            for (int j = 0; j < 4; ++j)
                #pragma unroll
                for (int r = 0; r < 4; ++r)
                    o[t2][j][r] *= alpha[r];

            // P: C-layout -> LDS (wave-private)
            #pragma unroll
            for (int j = 0; j < 4; ++j)
                #pragma unroll
                for (int r = 0; r < 4; ++r)
                    Ps[w][t2][lg * 4 + r][j * 16 + lm] = f2bf(sc[t2][j][r]);
        }

        // all 64 lanes' ds_writes drained before cross-lane ds_read
        __asm__ __volatile__("s_waitcnt lgkmcnt(0)" ::: "memory");

        // O += P V  (16 MFMAs)
        #pragma unroll
        for (int kk = 0; kk < 2; ++kk)
            #pragma unroll
            for (int t2 = 0; t2 < 2; ++t2) {
                short8 pf = *(const short8*)&Ps[w][t2][lm][kk * 32 + lg * 8];
                #pragma unroll
                for (int j = 0; j < 4; ++j)
                    o[t2][j] = __builtin_amdgcn_mfma_f32_16x16x32_bf16(pf, vf[kk][j], o[t2][j], 0, 0, 0);
            }
    }

    // epilogue: ctx[b*2048+s][h*64+d] = o / l   (bf16)
    const int b = bh >> 4, h = bh & 15;
    #pragma unroll
    for (int t2 = 0; t2 < 2; ++t2)
        #pragma unroll
        for (int r = 0; r < 4; ++r) {
            float inv = 1.f / l_i[t2][r];
            int s = qr0 + t2 * 16 + lg * 4 + r;
            size_t base = ((size_t)(b * S_ + s) << 10) + (h << 6);
            #pragma unroll
            for (int j = 0; j < 4; ++j)
                ctx[base + j * 16 + lm] = f2bf(o[t2][j][r] * inv);
        }
}

// ---------------------------------------------------------------------------
extern "C" void kernel_launch(void* const* d_in, const int* in_sizes, int n_in,
                              void* d_out, int out_size, void* d_ws, size_t ws_size,
                              hipStream_t stream) {
    const float* X  = (const float*)d_in[0];
    // d_in[1] = mask (causal tril; implemented analytically)
    const float* Wq = (const float*)d_in[2];
    const float* bq = (const float*)d_in[3];
    const float* Wk = (const float*)d_in[4];
    const float* bk = (const float*)d_in[5];
    const float* Wv = (const float*)d_in[6];
    const float* bv = (const float*)d_in[7];
    const float* Wo = (const float*)d_in[8];
    const float* bo = (const float*)d_in[9];
    float* out = (float*)d_out;

    short* ws  = (short*)d_ws;
    short* Xb  = ws;                          // 4,194,304 bf16
    short* Wb  = Xb + 4194304;                // [Wq|Wk|Wv|Wo] 4x1,048,576
    short* Qh  = Wb + 4194304;                // [bh][s][64]
    short* Kb  = Qh + 4194304;                // [bh][s][64]
    short* Vt  = Kb + 4194304;                // [bh][64][s]
    short* Ctx = Vt + 4194304;                // [b*s][1024]

    cast_kernel<<<8192, 256, 0, stream>>>(X, Wq, Wk, Wv, Wo, Xb, Wb);

    // fused QKV projection: N = 3072 (W rows [Wq|Wk|Wv]), out base = Qh
    gemm_kernel<128, 0><<<dim3(24, 32), 256, 0, stream>>>(
        Xb, Wb, bq, bk, bv, Qh, M_, 3 * D_, D_);

    attn_kernel<<<dim3(16, B_ * H_), 256, 0, stream>>>(Qh, Kb, Vt, Ctx);

    // output projection: fp32 out
    gemm_kernel<64, 2><<<dim3(16, 32), 256, 0, stream>>>(
        Ctx, Wb + 3145728, bo, bo, bo, out, M_, D_, D_);
}

// Round 3
// 396.530 us; speedup vs baseline: 1.0085x; 1.0085x over previous
//
#include <hip/hip_runtime.h>

// ---------------------------------------------------------------------------
// MultiHeadAttention: B=2, S=2048, H=16, Dh=64, D=1024, causal mask, fp32 I/O.
// R3: QKV GEMM writes V in natural layout (no scatter); separate LDS
//     transpose kernel makes Vt. Attention stays barrier-free (R2).
// ---------------------------------------------------------------------------

#define B_   2
#define S_   2048
#define H_   16
#define DH_  64
#define D_   1024
#define M_   (B_ * S_)          // 4096 rows

typedef __attribute__((ext_vector_type(8))) short short8;
typedef __attribute__((ext_vector_type(4))) short short4_t;
typedef float v4f __attribute__((ext_vector_type(4)));

__device__ __forceinline__ short f2bf(float f) {
    union { float f; unsigned u; } v; v.f = f;
    unsigned r = v.u + 0x7fffu + ((v.u >> 16) & 1u);  // round-to-nearest-even
    return (short)(r >> 16);
}

// ---------------------------------------------------------------------------
// Kernel 1: cast X[4M] and Wq,Wk,Wv,Wo[1M each] fp32 -> bf16
// ---------------------------------------------------------------------------
__global__ __launch_bounds__(256) void cast_kernel(
    const float* __restrict__ X,
    const float* __restrict__ Wq, const float* __restrict__ Wk,
    const float* __restrict__ Wv, const float* __restrict__ Wo,
    short* __restrict__ Xb, short* __restrict__ Wb)
{
    const int NX4 = (M_ * D_) / 4;      // 1,048,576
    const int NW4 = (D_ * D_) / 4;      // 262,144
    int idx = blockIdx.x * 256 + threadIdx.x;   // grid: 2,097,152 total

    const float* src; short* dst; int off;
    if (idx < NX4) { src = X; dst = Xb; off = idx; }
    else {
        int r = idx - NX4;
        int sel = r >> 18;
        int o = r & (NW4 - 1);
        src = (sel == 0) ? Wq : (sel == 1) ? Wk : (sel == 2) ? Wv : Wo;
        dst = Wb + sel * (D_ * D_);
        off = o;
    }
    float4 f = ((const float4*)src)[off];
    short4_t s;
    s.x = f2bf(f.x); s.y = f2bf(f.y); s.z = f2bf(f.z); s.w = f2bf(f.w);
    *(short4_t*)(dst + (size_t)off * 4) = s;
}

// ---------------------------------------------------------------------------
// Kernel 2: C = A(bf16,[M,K]) @ W(bf16,[N,K])^T + bias.  BM=128, BK=64.
// Register-prefetch double buffering.
// MODE 0 (BN=128): fused QKV. N=3072; Q,K,V all -> bf16 [bh][s][64] natural.
// MODE 2 (BN=64):  fp32 out, [M,1024] (final projection).
// ---------------------------------------------------------------------------
template<int BN, int MODE>
__global__ __launch_bounds__(256) void gemm_kernel(
    const short* __restrict__ A, const short* __restrict__ W,
    const float* __restrict__ bq, const float* __restrict__ bk,
    const float* __restrict__ bv, void* __restrict__ out,
    int M, int N, int K)
{
    __shared__ __align__(16) short As[128][72];
    __shared__ __align__(16) short Bs[BN][72];

    const int t    = threadIdx.x;
    const int lane = t & 63;
    const int wave = t >> 6;
    const int m0 = blockIdx.y * 128;
    const int n0 = blockIdx.x * BN;

    const int wm = (wave >> 1) * 64;
    const int wn = (wave & 1) * (BN / 2);
    const int NJ = BN / 32;            // acc cols per wave (4 or 2)
    const int BIT = BN / 32;           // B staging iters

    v4f acc[4][4] = {};

    const int lrow = t >> 3;           // 0..31
    const int lcol = (t & 7) * 8;

    const short* Ap = A + (size_t)(m0 + lrow) * K + lcol;
    const short* Wp = W + (size_t)(n0 + lrow) * K + lcol;

    uint4 pa[4], pb[4];
    #pragma unroll
    for (int it = 0; it < 4; ++it) pa[it] = *(const uint4*)(Ap + (size_t)it * 32 * K);
    #pragma unroll
    for (int it = 0; it < BIT; ++it) pb[it] = *(const uint4*)(Wp + (size_t)it * 32 * K);

    for (int k0 = 0; k0 < K; k0 += 64) {
        __syncthreads();
        #pragma unroll
        for (int it = 0; it < 4; ++it) *(uint4*)&As[lrow + it * 32][lcol] = pa[it];
        #pragma unroll
        for (int it = 0; it < BIT; ++it) *(uint4*)&Bs[lrow + it * 32][lcol] = pb[it];

        if (k0 + 64 < K) {
            #pragma unroll
            for (int it = 0; it < 4; ++it)
                pa[it] = *(const uint4*)(Ap + (k0 + 64) + (size_t)it * 32 * K);
            #pragma unroll
            for (int it = 0; it < BIT; ++it)
                pb[it] = *(const uint4*)(Wp + (k0 + 64) + (size_t)it * 32 * K);
        }
        __syncthreads();

        #pragma unroll
        for (int kk = 0; kk < 2; ++kk) {
            const int fr = lane & 15;
            const int fo = kk * 32 + (lane >> 4) * 8;
            short8 af[4], bf[4];
            #pragma unroll
            for (int i = 0; i < 4; ++i) af[i] = *(const short8*)&As[wm + i * 16 + fr][fo];
            #pragma unroll
            for (int j = 0; j < NJ; ++j) bf[j] = *(const short8*)&Bs[wn + j * 16 + fr][fo];
            #pragma unroll
            for (int i = 0; i < 4; ++i)
                #pragma unroll
                for (int j = 0; j < NJ; ++j)
                    acc[i][j] = __builtin_amdgcn_mfma_f32_16x16x32_bf16(af[i], bf[j], acc[i][j], 0, 0, 0);
        }
    }

    // Epilogue.  C/D layout: col = lane&15, row = (lane>>4)*4 + r
    const int colb = n0 + wn + (lane & 15);
    const int rowb = m0 + wm + (lane >> 4) * 4;
    const int sel  = n0 >> 10;   // block-uniform for MODE 0
    const float* bias = (MODE == 2) ? bq : (sel == 0) ? bq : (sel == 1) ? bk : bv;
    short* outQKV = (short*)out;   // [Qh | Kb | Vh], each 4,194,304 shorts

    #pragma unroll
    for (int j = 0; j < NJ; ++j) {
        int col = colb + j * 16;
        float bv_ = bias[col & 1023];
        #pragma unroll
        for (int i = 0; i < 4; ++i) {
            #pragma unroll
            for (int r = 0; r < 4; ++r) {
                int row = rowb + i * 16 + r;
                float v = acc[i][j][r] + bv_;
                if (MODE == 2) {
                    ((float*)out)[(size_t)row * 1024 + col] = v;
                } else {
                    int c = col & 1023;
                    int b = row >> 11, s = row & 2047, h = c >> 6, d = c & 63;
                    int bh = (b << 4) + h;
                    outQKV[(size_t)sel * 4194304 + ((size_t)bh * S_ + s) * DH_ + d] = f2bf(v);
                }
            }
        }
    }
}

// ---------------------------------------------------------------------------
// Kernel 2b: transpose Vh [bh][s][64] -> Vt [bh][64][s] via padded LDS tile.
// Coalesced 16B reads and 16B writes.  Grid (32 s-tiles, 32 bh), 256 thr.
// ---------------------------------------------------------------------------
__global__ __launch_bounds__(256) void vtrans_kernel(
    const short* __restrict__ Vh, short* __restrict__ Vt)
{
    __shared__ short tile[64][72];
    const int t  = threadIdx.x;
    const int s0 = blockIdx.x * 64;
    const int bh = blockIdx.y;
    const int r  = t >> 3;          // 0..31
    const int c  = (t & 7) * 8;     // 0..56

    #pragma unroll
    for (int it = 0; it < 2; ++it) {
        int srow = r + it * 32;
        *(uint4*)&tile[srow][c] =
            *(const uint4*)(Vh + ((size_t)bh * S_ + s0 + srow) * DH_ + c);
    }
    __syncthreads();
    #pragma unroll
    for (int it = 0; it < 2; ++it) {
        int d = r + it * 32;
        short4_t v0, v1;
        v0.x = tile[c + 0][d]; v0.y = tile[c + 1][d];
        v0.z = tile[c + 2][d]; v0.w = tile[c + 3][d];
        v1.x = tile[c + 4][d]; v1.y = tile[c + 5][d];
        v1.z = tile[c + 6][d]; v1.w = tile[c + 7][d];
        short* dst = Vt + ((size_t)bh << 17) + ((size_t)d << 11) + s0 + c;
        *(short4_t*)dst = v0;
        *(short4_t*)(dst + 4) = v1;
    }
}

// ---------------------------------------------------------------------------
// Kernel 3: causal flash attention — barrier-free (unchanged from R2).
// ---------------------------------------------------------------------------
__global__ __launch_bounds__(256, 2) void attn_kernel(
    const short* __restrict__ Q, const short* __restrict__ Kh,
    const short* __restrict__ Vt, short* __restrict__ ctx)
{
    __shared__ __align__(16) short Ps[4][2][16][72];

    const int t    = threadIdx.x;
    const int lane = t & 63;
    const int w    = t >> 6;
    const int p    = 63 - (blockIdx.x * 4 + w);
    const int bh   = blockIdx.y;
    const int qr0  = p * 32;
    const int ktmax = (qr0 + 31) >> 6;

    const int lm = lane & 15;
    const int lg = lane >> 4;

    const short* Qb = Q  + ((size_t)bh * S_) * DH_;
    const short* Kb = Kh + ((size_t)bh * S_) * DH_;
    const short* Vb = Vt + ((size_t)bh << 17);

    short8 qf[2][2];
    #pragma unroll
    for (int t2 = 0; t2 < 2; ++t2)
        #pragma unroll
        for (int kk = 0; kk < 2; ++kk)
            qf[t2][kk] = *(const short8*)(Qb + (size_t)(qr0 + t2 * 16 + lm) * DH_ + kk * 32 + lg * 8);

    float m_i[2][4], l_i[2][4];
    v4f o[2][4] = {};
    #pragma unroll
    for (int t2 = 0; t2 < 2; ++t2)
        #pragma unroll
        for (int r = 0; r < 4; ++r) { m_i[t2][r] = -1e30f; l_i[t2][r] = 0.f; }

    for (int kt = 0; kt <= ktmax; ++kt) {
        const int kv0 = kt * 64;

        short8 kf[2][4], vf[2][4];
        #pragma unroll
        for (int kk = 0; kk < 2; ++kk)
            #pragma unroll
            for (int j = 0; j < 4; ++j) {
                kf[kk][j] = *(const short8*)(Kb + (size_t)(kv0 + j * 16 + lm) * DH_ + kk * 32 + lg * 8);
                vf[kk][j] = *(const short8*)(Vb + ((size_t)(j * 16 + lm) << 11) + kv0 + kk * 32 + lg * 8);
            }

        v4f sc[2][4] = {};
        #pragma unroll
        for (int kk = 0; kk < 2; ++kk)
            #pragma unroll
            for (int t2 = 0; t2 < 2; ++t2)
                #pragma unroll
                for (int j = 0; j < 4; ++j)
                    sc[t2][j] = __builtin_amdgcn_mfma_f32_16x16x32_bf16(qf[t2][kk], kf[kk][j], sc[t2][j], 0, 0, 0);

        #pragma unroll
        for (int t2 = 0; t2 < 2; ++t2) {
            float rm[4];
            const int rowb = qr0 + t2 * 16 + lg * 4;
            #pragma unroll
            for (int r = 0; r < 4; ++r) rm[r] = -1e30f;
            if (kt == ktmax) {
                #pragma unroll
                for (int j = 0; j < 4; ++j) {
                    int col = kv0 + j * 16 + lm;
                    #pragma unroll
                    for (int r = 0; r < 4; ++r) {
                        float v = sc[t2][j][r] * 0.125f;
                        if (col > rowb + r) v = -1e30f;
                        sc[t2][j][r] = v;
                        rm[r] = fmaxf(rm[r], v);
                    }
                }
            } else {
                #pragma unroll
                for (int j = 0; j < 4; ++j)
                    #pragma unroll
                    for (int r = 0; r < 4; ++r) {
                        float v = sc[t2][j][r] * 0.125f;
                        sc[t2][j][r] = v;
                        rm[r] = fmaxf(rm[r], v);
                    }
            }
            #pragma unroll
            for (int off = 1; off < 16; off <<= 1)
                #pragma unroll
                for (int r = 0; r < 4; ++r)
                    rm[r] = fmaxf(rm[r], __shfl_xor(rm[r], off, 64));

            float alpha[4], rs[4];
            #pragma unroll
            for (int r = 0; r < 4; ++r) {
                float mn = fmaxf(m_i[t2][r], rm[r]);
                alpha[r] = __expf(m_i[t2][r] - mn);
                m_i[t2][r] = mn;
                rs[r] = 0.f;
                #pragma unroll
                for (int j = 0; j < 4; ++j) {
                    float e = __expf(sc[t2][j][r] - mn);
                    sc[t2][j][r] = e;
                    rs[r] += e;
                }
            }
            #pragma unroll
            for (int off = 1; off < 16; off <<= 1)
                #pragma unroll
                for (int r = 0; r < 4; ++r)
                    rs[r] += __shfl_xor(rs[r], off, 64);
            #pragma unroll
            for (int r = 0; r < 4; ++r) l_i[t2][r] = l_i[t2][r] * alpha[r] + rs[r];
            #pragma unroll
            for (int j = 0; j < 4; ++j)
                #pragma unroll
                for (int r = 0; r < 4; ++r)
                    o[t2][j][r] *= alpha[r];

            #pragma unroll
            for (int j = 0; j < 4; ++j)
                #pragma unroll
                for (int r = 0; r < 4; ++r)
                    Ps[w][t2][lg * 4 + r][j * 16 + lm] = f2bf(sc[t2][j][r]);
        }

        __asm__ __volatile__("s_waitcnt lgkmcnt(0)" ::: "memory");

        #pragma unroll
        for (int kk = 0; kk < 2; ++kk)
            #pragma unroll
            for (int t2 = 0; t2 < 2; ++t2) {
                short8 pf = *(const short8*)&Ps[w][t2][lm][kk * 32 + lg * 8];
                #pragma unroll
                for (int j = 0; j < 4; ++j)
                    o[t2][j] = __builtin_amdgcn_mfma_f32_16x16x32_bf16(pf, vf[kk][j], o[t2][j], 0, 0, 0);
            }
    }

    const int b = bh >> 4, h = bh & 15;
    #pragma unroll
    for (int t2 = 0; t2 < 2; ++t2)
        #pragma unroll
        for (int r = 0; r < 4; ++r) {
            float inv = 1.f / l_i[t2][r];
            int s = qr0 + t2 * 16 + lg * 4 + r;
            size_t base = ((size_t)(b * S_ + s) << 10) + (h << 6);
            #pragma unroll
            for (int j = 0; j < 4; ++j)
                ctx[base + j * 16 + lm] = f2bf(o[t2][j][r] * inv);
        }
}

// ---------------------------------------------------------------------------
extern "C" void kernel_launch(void* const* d_in, const int* in_sizes, int n_in,
                              void* d_out, int out_size, void* d_ws, size_t ws_size,
                              hipStream_t stream) {
    const float* X  = (const float*)d_in[0];
    const float* Wq = (const float*)d_in[2];
    const float* bq = (const float*)d_in[3];
    const float* Wk = (const float*)d_in[4];
    const float* bk = (const float*)d_in[5];
    const float* Wv = (const float*)d_in[6];
    const float* bv = (const float*)d_in[7];
    const float* Wo = (const float*)d_in[8];
    const float* bo = (const float*)d_in[9];
    float* out = (float*)d_out;

    short* ws  = (short*)d_ws;
    short* Xb  = ws;                          // 4,194,304 (reused as Vt later)
    short* Wb  = Xb + 4194304;                // [Wq|Wk|Wv|Wo]
    short* Qh  = Wb + 4194304;                // [bh][s][64]
    short* Kb  = Qh + 4194304;                // [bh][s][64]
    short* Vh  = Kb + 4194304;                // [bh][s][64] natural
    short* Ctx = Vh + 4194304;                // [b*s][1024]
    short* Vt  = Xb;                          // [bh][64][s]  (Xb is dead by then)

    cast_kernel<<<8192, 256, 0, stream>>>(X, Wq, Wk, Wv, Wo, Xb, Wb);

    // fused QKV projection: N = 3072, writes [Qh|Kb|Vh] natural layout
    gemm_kernel<128, 0><<<dim3(24, 32), 256, 0, stream>>>(
        Xb, Wb, bq, bk, bv, Qh, M_, 3 * D_, D_);

    vtrans_kernel<<<dim3(32, 32), 256, 0, stream>>>(Vh, Vt);

    attn_kernel<<<dim3(16, B_ * H_), 256, 0, stream>>>(Qh, Kb, Vt, Ctx);

    // output projection: fp32 out
    gemm_kernel<64, 2><<<dim3(16, 32), 256, 0, stream>>>(
        Ctx, Wb + 3145728, bo, bo, bo, out, M_, D_, D_);
}

// Round 4
// 367.108 us; speedup vs baseline: 1.0894x; 1.0801x over previous
//
#include <hip/hip_runtime.h>

// ---------------------------------------------------------------------------
// MultiHeadAttention: B=2, S=2048, H=16, Dh=64, D=1024, causal mask, fp32 I/O.
// R4: wide (16B/lane) epilogue stores via LDS transpose — R3 showed 2B scalar
//     stores in the GEMM epilogue cost 32B HBM sectors each (409 MB vs 25 MB).
// ---------------------------------------------------------------------------

#define B_   2
#define S_   2048
#define H_   16
#define DH_  64
#define D_   1024
#define M_   (B_ * S_)          // 4096 rows

typedef __attribute__((ext_vector_type(8))) short short8;
typedef __attribute__((ext_vector_type(4))) short short4_t;
typedef float v4f __attribute__((ext_vector_type(4)));

__device__ __forceinline__ short f2bf(float f) {
    union { float f; unsigned u; } v; v.f = f;
    unsigned r = v.u + 0x7fffu + ((v.u >> 16) & 1u);  // round-to-nearest-even
    return (short)(r >> 16);
}

// ---------------------------------------------------------------------------
// Kernel 1: cast X and Wq,Wk,Wv,Wo fp32 -> bf16.  8 elems/thread, 16B stores.
// ---------------------------------------------------------------------------
__global__ __launch_bounds__(256) void cast_kernel(
    const float* __restrict__ X,
    const float* __restrict__ Wq, const float* __restrict__ Wk,
    const float* __restrict__ Wv, const float* __restrict__ Wo,
    short* __restrict__ Xb, short* __restrict__ Wb)
{
    const int NX8 = (M_ * D_) / 8;      // 524,288
    const int NW8 = (D_ * D_) / 8;      // 131,072
    int idx = blockIdx.x * 256 + threadIdx.x;   // grid: 1,048,576 threads

    const float* src; short* dst; int off;
    if (idx < NX8) { src = X; dst = Xb; off = idx; }
    else {
        int r = idx - NX8;
        int sel = r >> 17;              // /NW8
        int o = r & (NW8 - 1);
        src = (sel == 0) ? Wq : (sel == 1) ? Wk : (sel == 2) ? Wv : Wo;
        dst = Wb + sel * (D_ * D_);
        off = o;
    }
    float4 f0 = ((const float4*)src)[off * 2];
    float4 f1 = ((const float4*)src)[off * 2 + 1];
    short8 s;
    s[0] = f2bf(f0.x); s[1] = f2bf(f0.y); s[2] = f2bf(f0.z); s[3] = f2bf(f0.w);
    s[4] = f2bf(f1.x); s[5] = f2bf(f1.y); s[6] = f2bf(f1.z); s[7] = f2bf(f1.w);
    *(short8*)(dst + (size_t)off * 8) = s;
}

// ---------------------------------------------------------------------------
// Kernel 2: C = A(bf16,[M,K]) @ W(bf16,[N,K])^T + bias.  BM=128, BK=64,
// register-prefetch double buffering.
// MODE 0 (BN=128): fused QKV, N=3072.  Epilogue: LDS transpose -> 16B/lane
//   bf16 stores into [bh][s][64] natural layout for Q,K,V.
// MODE 2 (BN=64):  fp32 out [M,1024] (full-line stores per instruction).
// ---------------------------------------------------------------------------
template<int BN, int MODE>
__global__ __launch_bounds__(256) void gemm_kernel(
    const short* __restrict__ A, const short* __restrict__ W,
    const float* __restrict__ bq, const float* __restrict__ bk,
    const float* __restrict__ bv, void* __restrict__ out,
    int M, int N, int K)
{
    __shared__ __align__(16) short smem[(128 + BN) * 72];
    short (*As)[72] = (short(*)[72])smem;
    short (*Bs)[72] = (short(*)[72])(smem + 128 * 72);

    const int t    = threadIdx.x;
    const int lane = t & 63;
    const int wave = t >> 6;
    const int m0 = blockIdx.y * 128;
    const int n0 = blockIdx.x * BN;

    const int wm = (wave >> 1) * 64;
    const int wn = (wave & 1) * (BN / 2);
    const int NJ = BN / 32;            // acc cols per wave (4 or 2)
    const int BIT = BN / 32;           // B staging iters

    v4f acc[4][4] = {};

    const int lrow = t >> 3;           // 0..31
    const int lcol = (t & 7) * 8;

    const short* Ap = A + (size_t)(m0 + lrow) * K + lcol;
    const short* Wp = W + (size_t)(n0 + lrow) * K + lcol;

    uint4 pa[4], pb[4];
    #pragma unroll
    for (int it = 0; it < 4; ++it) pa[it] = *(const uint4*)(Ap + (size_t)it * 32 * K);
    #pragma unroll
    for (int it = 0; it < BIT; ++it) pb[it] = *(const uint4*)(Wp + (size_t)it * 32 * K);

    for (int k0 = 0; k0 < K; k0 += 64) {
        __syncthreads();
        #pragma unroll
        for (int it = 0; it < 4; ++it) *(uint4*)&As[lrow + it * 32][lcol] = pa[it];
        #pragma unroll
        for (int it = 0; it < BIT; ++it) *(uint4*)&Bs[lrow + it * 32][lcol] = pb[it];

        if (k0 + 64 < K) {
            #pragma unroll
            for (int it = 0; it < 4; ++it)
                pa[it] = *(const uint4*)(Ap + (k0 + 64) + (size_t)it * 32 * K);
            #pragma unroll
            for (int it = 0; it < BIT; ++it)
                pb[it] = *(const uint4*)(Wp + (k0 + 64) + (size_t)it * 32 * K);
        }
        __syncthreads();

        #pragma unroll
        for (int kk = 0; kk < 2; ++kk) {
            const int fr = lane & 15;
            const int fo = kk * 32 + (lane >> 4) * 8;
            short8 af[4], bf[4];
            #pragma unroll
            for (int i = 0; i < 4; ++i) af[i] = *(const short8*)&As[wm + i * 16 + fr][fo];
            #pragma unroll
            for (int j = 0; j < NJ; ++j) bf[j] = *(const short8*)&Bs[wn + j * 16 + fr][fo];
            #pragma unroll
            for (int i = 0; i < 4; ++i)
                #pragma unroll
                for (int j = 0; j < NJ; ++j)
                    acc[i][j] = __builtin_amdgcn_mfma_f32_16x16x32_bf16(af[i], bf[j], acc[i][j], 0, 0, 0);
        }
    }

    const int lm = lane & 15;
    const int lg = lane >> 4;
    const int sel  = n0 >> 10;   // block-uniform for MODE 0
    const float* bias = (MODE == 2) ? bq : (sel == 0) ? bq : (sel == 1) ? bk : bv;

    if (MODE == 2) {
        // fp32 direct: each quarter-wave covers a full 64B line per store.
        const int colb = n0 + wn + lm;
        const int rowb = m0 + wm + lg * 4;
        #pragma unroll
        for (int j = 0; j < NJ; ++j) {
            int col = colb + j * 16;
            float bv_ = bias[col];
            #pragma unroll
            for (int i = 0; i < 4; ++i)
                #pragma unroll
                for (int r = 0; r < 4; ++r)
                    ((float*)out)[(size_t)(rowb + i * 16 + r) * 1024 + col] = acc[i][j][r] + bv_;
        }
    } else {
        // bf16: stage wave's 64x64 tile in LDS, read back 16B/lane, store wide.
        __syncthreads();                       // main-loop LDS reads all done
        short* Es = smem + wave * (64 * 72);   // wave-private 64x72 region
        const int cb = (n0 + wn) & 1023;       // bias col base (h-aligned 64)
        #pragma unroll
        for (int j = 0; j < 4; ++j) {
            float bv_ = bias[cb + j * 16 + lm];
            #pragma unroll
            for (int i = 0; i < 4; ++i)
                #pragma unroll
                for (int r = 0; r < 4; ++r)
                    Es[(i * 16 + lg * 4 + r) * 72 + j * 16 + lm] = f2bf(acc[i][j][r] + bv_);
        }
        __asm__ __volatile__("s_waitcnt lgkmcnt(0)" ::: "memory");
        short* outQKV = (short*)out;           // [Qh | Kb | Vh]
        const int rl = lane >> 3;              // 0..7
        const int c8 = (lane & 7) * 8;         // 0..56
        #pragma unroll
        for (int it = 0; it < 8; ++it) {
            int row_l = it * 8 + rl;
            short8 vrow = *(const short8*)&Es[row_l * 72 + c8];
            int grow = m0 + wm + row_l;
            int c = (n0 + wn + c8) & 1023;
            int b = grow >> 11, s = grow & 2047, h = c >> 6, d = c & 63;
            int bh = (b << 4) + h;
            *(short8*)(outQKV + (size_t)sel * 4194304 + ((size_t)bh * S_ + s) * DH_ + d) = vrow;
        }
    }
}

// ---------------------------------------------------------------------------
// Kernel 2b: transpose Vh [bh][s][64] -> Vt [bh][64][s].  16B r/w.
// ---------------------------------------------------------------------------
__global__ __launch_bounds__(256) void vtrans_kernel(
    const short* __restrict__ Vh, short* __restrict__ Vt)
{
    __shared__ short tile[64][72];
    const int t  = threadIdx.x;
    const int s0 = blockIdx.x * 64;
    const int bh = blockIdx.y;
    const int r  = t >> 3;          // 0..31
    const int c  = (t & 7) * 8;     // 0..56

    #pragma unroll
    for (int it = 0; it < 2; ++it) {
        int srow = r + it * 32;
        *(uint4*)&tile[srow][c] =
            *(const uint4*)(Vh + ((size_t)bh * S_ + s0 + srow) * DH_ + c);
    }
    __syncthreads();
    #pragma unroll
    for (int it = 0; it < 2; ++it) {
        int d = r + it * 32;
        short8 v;
        #pragma unroll
        for (int u = 0; u < 8; ++u) v[u] = tile[c + u][d];
        *(short8*)(Vt + ((size_t)bh << 17) + ((size_t)d << 11) + s0 + c) = v;
    }
}

// ---------------------------------------------------------------------------
// Kernel 3: causal flash attention — barrier-free; paired long/short waves.
// ---------------------------------------------------------------------------
__global__ __launch_bounds__(256, 2) void attn_kernel(
    const short* __restrict__ Q, const short* __restrict__ Kh,
    const short* __restrict__ Vt, short* __restrict__ ctx)
{
    __shared__ __align__(16) short Ps[4][2][16][72];

    const int t    = threadIdx.x;
    const int lane = t & 63;
    const int w    = t >> 6;
    // pair 2 short + 2 long diagonal strips per block -> uniform block work
    const int p    = (w < 2) ? (blockIdx.x * 2 + w)
                             : (63 - (blockIdx.x * 2 + (w - 2)));
    const int bh   = blockIdx.y;
    const int qr0  = p * 32;
    const int ktmax = (qr0 + 31) >> 6;

    const int lm = lane & 15;
    const int lg = lane >> 4;

    const short* Qb = Q  + ((size_t)bh * S_) * DH_;
    const short* Kb = Kh + ((size_t)bh * S_) * DH_;
    const short* Vb = Vt + ((size_t)bh << 17);

    short8 qf[2][2];
    #pragma unroll
    for (int t2 = 0; t2 < 2; ++t2)
        #pragma unroll
        for (int kk = 0; kk < 2; ++kk)
            qf[t2][kk] = *(const short8*)(Qb + (size_t)(qr0 + t2 * 16 + lm) * DH_ + kk * 32 + lg * 8);

    float m_i[2][4], l_i[2][4];
    v4f o[2][4] = {};
    #pragma unroll
    for (int t2 = 0; t2 < 2; ++t2)
        #pragma unroll
        for (int r = 0; r < 4; ++r) { m_i[t2][r] = -1e30f; l_i[t2][r] = 0.f; }

    for (int kt = 0; kt <= ktmax; ++kt) {
        const int kv0 = kt * 64;

        short8 kf[2][4], vf[2][4];
        #pragma unroll
        for (int kk = 0; kk < 2; ++kk)
            #pragma unroll
            for (int j = 0; j < 4; ++j) {
                kf[kk][j] = *(const short8*)(Kb + (size_t)(kv0 + j * 16 + lm) * DH_ + kk * 32 + lg * 8);
                vf[kk][j] = *(const short8*)(Vb + ((size_t)(j * 16 + lm) << 11) + kv0 + kk * 32 + lg * 8);
            }

        v4f sc[2][4] = {};
        #pragma unroll
        for (int kk = 0; kk < 2; ++kk)
            #pragma unroll
            for (int t2 = 0; t2 < 2; ++t2)
                #pragma unroll
                for (int j = 0; j < 4; ++j)
                    sc[t2][j] = __builtin_amdgcn_mfma_f32_16x16x32_bf16(qf[t2][kk], kf[kk][j], sc[t2][j], 0, 0, 0);

        #pragma unroll
        for (int t2 = 0; t2 < 2; ++t2) {
            float rm[4];
            const int rowb = qr0 + t2 * 16 + lg * 4;
            #pragma unroll
            for (int r = 0; r < 4; ++r) rm[r] = -1e30f;
            if (kt == ktmax) {
                #pragma unroll
                for (int j = 0; j < 4; ++j) {
                    int col = kv0 + j * 16 + lm;
                    #pragma unroll
                    for (int r = 0; r < 4; ++r) {
                        float v = sc[t2][j][r] * 0.125f;
                        if (col > rowb + r) v = -1e30f;
                        sc[t2][j][r] = v;
                        rm[r] = fmaxf(rm[r], v);
                    }
                }
            } else {
                #pragma unroll
                for (int j = 0; j < 4; ++j)
                    #pragma unroll
                    for (int r = 0; r < 4; ++r) {
                        float v = sc[t2][j][r] * 0.125f;
                        sc[t2][j][r] = v;
                        rm[r] = fmaxf(rm[r], v);
                    }
            }
            #pragma unroll
            for (int off = 1; off < 16; off <<= 1)
                #pragma unroll
                for (int r = 0; r < 4; ++r)
                    rm[r] = fmaxf(rm[r], __shfl_xor(rm[r], off, 64));

            float alpha[4], rs[4];
            #pragma unroll
            for (int r = 0; r < 4; ++r) {
                float mn = fmaxf(m_i[t2][r], rm[r]);
                alpha[r] = __expf(m_i[t2][r] - mn);
                m_i[t2][r] = mn;
                rs[r] = 0.f;
                #pragma unroll
                for (int j = 0; j < 4; ++j) {
                    float e = __expf(sc[t2][j][r] - mn);
                    sc[t2][j][r] = e;
                    rs[r] += e;
                }
            }
            #pragma unroll
            for (int off = 1; off < 16; off <<= 1)
                #pragma unroll
                for (int r = 0; r < 4; ++r)
                    rs[r] += __shfl_xor(rs[r], off, 64);
            #pragma unroll
            for (int r = 0; r < 4; ++r) l_i[t2][r] = l_i[t2][r] * alpha[r] + rs[r];
            #pragma unroll
            for (int j = 0; j < 4; ++j)
                #pragma unroll
                for (int r = 0; r < 4; ++r)
                    o[t2][j][r] *= alpha[r];

            #pragma unroll
            for (int j = 0; j < 4; ++j)
                #pragma unroll
                for (int r = 0; r < 4; ++r)
                    Ps[w][t2][lg * 4 + r][j * 16 + lm] = f2bf(sc[t2][j][r]);
        }

        __asm__ __volatile__("s_waitcnt lgkmcnt(0)" ::: "memory");

        #pragma unroll
        for (int kk = 0; kk < 2; ++kk)
            #pragma unroll
            for (int t2 = 0; t2 < 2; ++t2) {
                short8 pf = *(const short8*)&Ps[w][t2][lm][kk * 32 + lg * 8];
                #pragma unroll
                for (int j = 0; j < 4; ++j)
                    o[t2][j] = __builtin_amdgcn_mfma_f32_16x16x32_bf16(pf, vf[kk][j], o[t2][j], 0, 0, 0);
            }
    }

    const int b = bh >> 4, h = bh & 15;
    #pragma unroll
    for (int t2 = 0; t2 < 2; ++t2)
        #pragma unroll
        for (int r = 0; r < 4; ++r) {
            float inv = 1.f / l_i[t2][r];
            int s = qr0 + t2 * 16 + lg * 4 + r;
            size_t base = ((size_t)(b * S_ + s) << 10) + (h << 6);
            #pragma unroll
            for (int j = 0; j < 4; ++j)
                ctx[base + j * 16 + lm] = f2bf(o[t2][j][r] * inv);
        }
}

// ---------------------------------------------------------------------------
extern "C" void kernel_launch(void* const* d_in, const int* in_sizes, int n_in,
                              void* d_out, int out_size, void* d_ws, size_t ws_size,
                              hipStream_t stream) {
    const float* X  = (const float*)d_in[0];
    const float* Wq = (const float*)d_in[2];
    const float* bq = (const float*)d_in[3];
    const float* Wk = (const float*)d_in[4];
    const float* bk = (const float*)d_in[5];
    const float* Wv = (const float*)d_in[6];
    const float* bv = (const float*)d_in[7];
    const float* Wo = (const float*)d_in[8];
    const float* bo = (const float*)d_in[9];
    float* out = (float*)d_out;

    short* ws  = (short*)d_ws;
    short* Xb  = ws;                          // reused as Vt after QKV gemm
    short* Wb  = Xb + 4194304;                // [Wq|Wk|Wv|Wo]
    short* Qh  = Wb + 4194304;                // [bh][s][64]
    short* Kb  = Qh + 4194304;                // [bh][s][64]
    short* Vh  = Kb + 4194304;                // [bh][s][64] natural
    short* Ctx = Vh + 4194304;                // [b*s][1024]
    short* Vt  = Xb;                          // [bh][64][s]

    cast_kernel<<<4096, 256, 0, stream>>>(X, Wq, Wk, Wv, Wo, Xb, Wb);

    gemm_kernel<128, 0><<<dim3(24, 32), 256, 0, stream>>>(
        Xb, Wb, bq, bk, bv, Qh, M_, 3 * D_, D_);

    vtrans_kernel<<<dim3(32, 32), 256, 0, stream>>>(Vh, Vt);

    attn_kernel<<<dim3(16, B_ * H_), 256, 0, stream>>>(Qh, Kb, Vt, Ctx);

    gemm_kernel<64, 2><<<dim3(16, 32), 256, 0, stream>>>(
        Ctx, Wb + 3145728, bo, bo, bo, out, M_, D_, D_);
}

// Round 5
// 356.875 us; speedup vs baseline: 1.1206x; 1.0287x over previous
//
#include <hip/hip_runtime.h>

// ---------------------------------------------------------------------------
// MultiHeadAttention: B=2, S=2048, H=16, Dh=64, D=1024, causal mask, fp32 I/O.
// R5: XCD-aware block swizzle (bid%8 = XCD; each XCD owns 4 by-rows / 4 bh)
//     to stop L2 thrash — R4 showed gemms fabric-bound (483 MB, 3.9 TB/s,
//     all pipes idle) with zero concurrent-block tile reuse.
// ---------------------------------------------------------------------------

#define B_   2
#define S_   2048
#define H_   16
#define DH_  64
#define D_   1024
#define M_   (B_ * S_)          // 4096 rows

typedef __attribute__((ext_vector_type(8))) short short8;
typedef __attribute__((ext_vector_type(4))) short short4_t;
typedef float v4f __attribute__((ext_vector_type(4)));

__device__ __forceinline__ short f2bf(float f) {
    union { float f; unsigned u; } v; v.f = f;
    unsigned r = v.u + 0x7fffu + ((v.u >> 16) & 1u);  // round-to-nearest-even
    return (short)(r >> 16);
}

// ---------------------------------------------------------------------------
// Kernel 1: cast X and Wq,Wk,Wv,Wo fp32 -> bf16.  8 elems/thread, 16B stores.
// ---------------------------------------------------------------------------
__global__ __launch_bounds__(256) void cast_kernel(
    const float* __restrict__ X,
    const float* __restrict__ Wq, const float* __restrict__ Wk,
    const float* __restrict__ Wv, const float* __restrict__ Wo,
    short* __restrict__ Xb, short* __restrict__ Wb)
{
    const int NX8 = (M_ * D_) / 8;      // 524,288
    const int NW8 = (D_ * D_) / 8;      // 131,072
    int idx = blockIdx.x * 256 + threadIdx.x;

    const float* src; short* dst; int off;
    if (idx < NX8) { src = X; dst = Xb; off = idx; }
    else {
        int r = idx - NX8;
        int sel = r >> 17;
        int o = r & (NW8 - 1);
        src = (sel == 0) ? Wq : (sel == 1) ? Wk : (sel == 2) ? Wv : Wo;
        dst = Wb + sel * (D_ * D_);
        off = o;
    }
    float4 f0 = ((const float4*)src)[off * 2];
    float4 f1 = ((const float4*)src)[off * 2 + 1];
    short8 s;
    s[0] = f2bf(f0.x); s[1] = f2bf(f0.y); s[2] = f2bf(f0.z); s[3] = f2bf(f0.w);
    s[4] = f2bf(f1.x); s[5] = f2bf(f1.y); s[6] = f2bf(f1.z); s[7] = f2bf(f1.w);
    *(short8*)(dst + (size_t)off * 8) = s;
}

// ---------------------------------------------------------------------------
// Kernel 2: C = A(bf16,[M,K]) @ W(bf16,[N,K])^T + bias.  BM=128, BK=64,
// register-prefetch double buffering.  FLAT grid (NBX*32 blocks), swizzled:
//   xcd = bid & 7, n = bid >> 3, by = 4*xcd + (n & 3), bx = bid >> 5.
// So each XCD keeps 4 A-tiles L2-resident and 4 concurrent blocks share
// each B-tile.
// MODE 0 (BN=128): fused QKV, N=3072, bf16 [bh][s][64] via LDS-transpose
//                  16B/lane stores.
// MODE 2 (BN=64):  fp32 out [M,1024].
// ---------------------------------------------------------------------------
template<int BN, int MODE>
__global__ __launch_bounds__(256) void gemm_kernel(
    const short* __restrict__ A, const short* __restrict__ W,
    const float* __restrict__ bq, const float* __restrict__ bk,
    const float* __restrict__ bv, void* __restrict__ out,
    int M, int N, int K)
{
    __shared__ __align__(16) short smem[(128 + BN) * 72];
    short (*As)[72] = (short(*)[72])smem;
    short (*Bs)[72] = (short(*)[72])(smem + 128 * 72);

    const int t    = threadIdx.x;
    const int lane = t & 63;
    const int wave = t >> 6;

    // XCD-aware swizzle (flat grid)
    const int bid = blockIdx.x;
    const int by  = ((bid & 7) << 2) + ((bid >> 3) & 3);
    const int bx  = bid >> 5;
    const int m0 = by * 128;
    const int n0 = bx * BN;

    const int wm = (wave >> 1) * 64;
    const int wn = (wave & 1) * (BN / 2);
    const int NJ = BN / 32;
    const int BIT = BN / 32;

    v4f acc[4][4] = {};

    const int lrow = t >> 3;
    const int lcol = (t & 7) * 8;

    const short* Ap = A + (size_t)(m0 + lrow) * K + lcol;
    const short* Wp = W + (size_t)(n0 + lrow) * K + lcol;

    uint4 pa[4], pb[4];
    #pragma unroll
    for (int it = 0; it < 4; ++it) pa[it] = *(const uint4*)(Ap + (size_t)it * 32 * K);
    #pragma unroll
    for (int it = 0; it < BIT; ++it) pb[it] = *(const uint4*)(Wp + (size_t)it * 32 * K);

    for (int k0 = 0; k0 < K; k0 += 64) {
        __syncthreads();
        #pragma unroll
        for (int it = 0; it < 4; ++it) *(uint4*)&As[lrow + it * 32][lcol] = pa[it];
        #pragma unroll
        for (int it = 0; it < BIT; ++it) *(uint4*)&Bs[lrow + it * 32][lcol] = pb[it];

        if (k0 + 64 < K) {
            #pragma unroll
            for (int it = 0; it < 4; ++it)
                pa[it] = *(const uint4*)(Ap + (k0 + 64) + (size_t)it * 32 * K);
            #pragma unroll
            for (int it = 0; it < BIT; ++it)
                pb[it] = *(const uint4*)(Wp + (k0 + 64) + (size_t)it * 32 * K);
        }
        __syncthreads();

        #pragma unroll
        for (int kk = 0; kk < 2; ++kk) {
            const int fr = lane & 15;
            const int fo = kk * 32 + (lane >> 4) * 8;
            short8 af[4], bf[4];
            #pragma unroll
            for (int i = 0; i < 4; ++i) af[i] = *(const short8*)&As[wm + i * 16 + fr][fo];
            #pragma unroll
            for (int j = 0; j < NJ; ++j) bf[j] = *(const short8*)&Bs[wn + j * 16 + fr][fo];
            #pragma unroll
            for (int i = 0; i < 4; ++i)
                #pragma unroll
                for (int j = 0; j < NJ; ++j)
                    acc[i][j] = __builtin_amdgcn_mfma_f32_16x16x32_bf16(af[i], bf[j], acc[i][j], 0, 0, 0);
        }
    }

    const int lm = lane & 15;
    const int lg = lane >> 4;
    const int sel  = n0 >> 10;
    const float* bias = (MODE == 2) ? bq : (sel == 0) ? bq : (sel == 1) ? bk : bv;

    if (MODE == 2) {
        const int colb = n0 + wn + lm;
        const int rowb = m0 + wm + lg * 4;
        #pragma unroll
        for (int j = 0; j < NJ; ++j) {
            int col = colb + j * 16;
            float bv_ = bias[col];
            #pragma unroll
            for (int i = 0; i < 4; ++i)
                #pragma unroll
                for (int r = 0; r < 4; ++r)
                    ((float*)out)[(size_t)(rowb + i * 16 + r) * 1024 + col] = acc[i][j][r] + bv_;
        }
    } else {
        __syncthreads();
        short* Es = smem + wave * (64 * 72);
        const int cb = (n0 + wn) & 1023;
        #pragma unroll
        for (int j = 0; j < 4; ++j) {
            float bv_ = bias[cb + j * 16 + lm];
            #pragma unroll
            for (int i = 0; i < 4; ++i)
                #pragma unroll
                for (int r = 0; r < 4; ++r)
                    Es[(i * 16 + lg * 4 + r) * 72 + j * 16 + lm] = f2bf(acc[i][j][r] + bv_);
        }
        __asm__ __volatile__("s_waitcnt lgkmcnt(0)" ::: "memory");
        short* outQKV = (short*)out;
        const int rl = lane >> 3;
        const int c8 = (lane & 7) * 8;
        #pragma unroll
        for (int it = 0; it < 8; ++it) {
            int row_l = it * 8 + rl;
            short8 vrow = *(const short8*)&Es[row_l * 72 + c8];
            int grow = m0 + wm + row_l;
            int c = (n0 + wn + c8) & 1023;
            int b = grow >> 11, s = grow & 2047, h = c >> 6, d = c & 63;
            int bh = (b << 4) + h;
            *(short8*)(outQKV + (size_t)sel * 4194304 + ((size_t)bh * S_ + s) * DH_ + d) = vrow;
        }
    }
}

// ---------------------------------------------------------------------------
// Kernel 2b: transpose Vh [bh][s][64] -> Vt [bh][64][s].  16B r/w.
// Swizzled: each XCD owns 4 bh.
// ---------------------------------------------------------------------------
__global__ __launch_bounds__(256) void vtrans_kernel(
    const short* __restrict__ Vh, short* __restrict__ Vt)
{
    __shared__ short tile[64][72];
    const int t  = threadIdx.x;
    const int bid = blockIdx.x;                 // 1024 blocks
    const int bh = ((bid & 7) << 2) + ((bid >> 3) & 3);
    const int s0 = (bid >> 5) * 64;
    const int r  = t >> 3;
    const int c  = (t & 7) * 8;

    #pragma unroll
    for (int it = 0; it < 2; ++it) {
        int srow = r + it * 32;
        *(uint4*)&tile[srow][c] =
            *(const uint4*)(Vh + ((size_t)bh * S_ + s0 + srow) * DH_ + c);
    }
    __syncthreads();
    #pragma unroll
    for (int it = 0; it < 2; ++it) {
        int d = r + it * 32;
        short8 v;
        #pragma unroll
        for (int u = 0; u < 8; ++u) v[u] = tile[c + u][d];
        *(short8*)(Vt + ((size_t)bh << 17) + ((size_t)d << 11) + s0 + c) = v;
    }
}

// ---------------------------------------------------------------------------
// Kernel 3: causal flash attention — barrier-free; paired long/short waves;
// flat grid of 512, swizzled so each XCD owns 4 bh (K/V L2-resident: 2 MB).
// ---------------------------------------------------------------------------
__global__ __launch_bounds__(256, 2) void attn_kernel(
    const short* __restrict__ Q, const short* __restrict__ Kh,
    const short* __restrict__ Vt, short* __restrict__ ctx)
{
    __shared__ __align__(16) short Ps[4][2][16][72];

    const int t    = threadIdx.x;
    const int lane = t & 63;
    const int w    = t >> 6;
    const int bid  = blockIdx.x;                // 512 blocks
    const int bh   = ((bid & 7) << 2) + ((bid >> 3) & 3);
    const int qp   = bid >> 5;                  // 0..15
    const int p    = (w < 2) ? (qp * 2 + w) : (63 - (qp * 2 + (w - 2)));
    const int qr0  = p * 32;
    const int ktmax = (qr0 + 31) >> 6;

    const int lm = lane & 15;
    const int lg = lane >> 4;

    const short* Qb = Q  + ((size_t)bh * S_) * DH_;
    const short* Kb = Kh + ((size_t)bh * S_) * DH_;
    const short* Vb = Vt + ((size_t)bh << 17);

    short8 qf[2][2];
    #pragma unroll
    for (int t2 = 0; t2 < 2; ++t2)
        #pragma unroll
        for (int kk = 0; kk < 2; ++kk)
            qf[t2][kk] = *(const short8*)(Qb + (size_t)(qr0 + t2 * 16 + lm) * DH_ + kk * 32 + lg * 8);

    float m_i[2][4], l_i[2][4];
    v4f o[2][4] = {};
    #pragma unroll
    for (int t2 = 0; t2 < 2; ++t2)
        #pragma unroll
        for (int r = 0; r < 4; ++r) { m_i[t2][r] = -1e30f; l_i[t2][r] = 0.f; }

    for (int kt = 0; kt <= ktmax; ++kt) {
        const int kv0 = kt * 64;

        short8 kf[2][4], vf[2][4];
        #pragma unroll
        for (int kk = 0; kk < 2; ++kk)
            #pragma unroll
            for (int j = 0; j < 4; ++j) {
                kf[kk][j] = *(const short8*)(Kb + (size_t)(kv0 + j * 16 + lm) * DH_ + kk * 32 + lg * 8);
                vf[kk][j] = *(const short8*)(Vb + ((size_t)(j * 16 + lm) << 11) + kv0 + kk * 32 + lg * 8);
            }

        v4f sc[2][4] = {};
        #pragma unroll
        for (int kk = 0; kk < 2; ++kk)
            #pragma unroll
            for (int t2 = 0; t2 < 2; ++t2)
                #pragma unroll
                for (int j = 0; j < 4; ++j)
                    sc[t2][j] = __builtin_amdgcn_mfma_f32_16x16x32_bf16(qf[t2][kk], kf[kk][j], sc[t2][j], 0, 0, 0);

        #pragma unroll
        for (int t2 = 0; t2 < 2; ++t2) {
            float rm[4];
            const int rowb = qr0 + t2 * 16 + lg * 4;
            #pragma unroll
            for (int r = 0; r < 4; ++r) rm[r] = -1e30f;
            if (kt == ktmax) {
                #pragma unroll
                for (int j = 0; j < 4; ++j) {
                    int col = kv0 + j * 16 + lm;
                    #pragma unroll
                    for (int r = 0; r < 4; ++r) {
                        float v = sc[t2][j][r] * 0.125f;
                        if (col > rowb + r) v = -1e30f;
                        sc[t2][j][r] = v;
                        rm[r] = fmaxf(rm[r], v);
                    }
                }
            } else {
                #pragma unroll
                for (int j = 0; j < 4; ++j)
                    #pragma unroll
                    for (int r = 0; r < 4; ++r) {
                        float v = sc[t2][j][r] * 0.125f;
                        sc[t2][j][r] = v;
                        rm[r] = fmaxf(rm[r], v);
                    }
            }
            #pragma unroll
            for (int off = 1; off < 16; off <<= 1)
                #pragma unroll
                for (int r = 0; r < 4; ++r)
                    rm[r] = fmaxf(rm[r], __shfl_xor(rm[r], off, 64));

            float alpha[4], rs[4];
            #pragma unroll
            for (int r = 0; r < 4; ++r) {
                float mn = fmaxf(m_i[t2][r], rm[r]);
                alpha[r] = __expf(m_i[t2][r] - mn);
                m_i[t2][r] = mn;
                rs[r] = 0.f;
                #pragma unroll
                for (int j = 0; j < 4; ++j) {
                    float e = __expf(sc[t2][j][r] - mn);
                    sc[t2][j][r] = e;
                    rs[r] += e;
                }
            }
            #pragma unroll
            for (int off = 1; off < 16; off <<= 1)
                #pragma unroll
                for (int r = 0; r < 4; ++r)
                    rs[r] += __shfl_xor(rs[r], off, 64);
            #pragma unroll
            for (int r = 0; r < 4; ++r) l_i[t2][r] = l_i[t2][r] * alpha[r] + rs[r];
            #pragma unroll
            for (int j = 0; j < 4; ++j)
                #pragma unroll
                for (int r = 0; r < 4; ++r)
                    o[t2][j][r] *= alpha[r];

            #pragma unroll
            for (int j = 0; j < 4; ++j)
                #pragma unroll
                for (int r = 0; r < 4; ++r)
                    Ps[w][t2][lg * 4 + r][j * 16 + lm] = f2bf(sc[t2][j][r]);
        }

        __asm__ __volatile__("s_waitcnt lgkmcnt(0)" ::: "memory");

        #pragma unroll
        for (int kk = 0; kk < 2; ++kk)
            #pragma unroll
            for (int t2 = 0; t2 < 2; ++t2) {
                short8 pf = *(const short8*)&Ps[w][t2][lm][kk * 32 + lg * 8];
                #pragma unroll
                for (int j = 0; j < 4; ++j)
                    o[t2][j] = __builtin_amdgcn_mfma_f32_16x16x32_bf16(pf, vf[kk][j], o[t2][j], 0, 0, 0);
            }
    }

    const int b = bh >> 4, h = bh & 15;
    #pragma unroll
    for (int t2 = 0; t2 < 2; ++t2)
        #pragma unroll
        for (int r = 0; r < 4; ++r) {
            float inv = 1.f / l_i[t2][r];
            int s = qr0 + t2 * 16 + lg * 4 + r;
            size_t base = ((size_t)(b * S_ + s) << 10) + (h << 6);
            #pragma unroll
            for (int j = 0; j < 4; ++j)
                ctx[base + j * 16 + lm] = f2bf(o[t2][j][r] * inv);
        }
}

// ---------------------------------------------------------------------------
extern "C" void kernel_launch(void* const* d_in, const int* in_sizes, int n_in,
                              void* d_out, int out_size, void* d_ws, size_t ws_size,
                              hipStream_t stream) {
    const float* X  = (const float*)d_in[0];
    const float* Wq = (const float*)d_in[2];
    const float* bq = (const float*)d_in[3];
    const float* Wk = (const float*)d_in[4];
    const float* bk = (const float*)d_in[5];
    const float* Wv = (const float*)d_in[6];
    const float* bv = (const float*)d_in[7];
    const float* Wo = (const float*)d_in[8];
    const float* bo = (const float*)d_in[9];
    float* out = (float*)d_out;

    short* ws  = (short*)d_ws;
    short* Xb  = ws;                          // reused as Vt after QKV gemm
    short* Wb  = Xb + 4194304;                // [Wq|Wk|Wv|Wo]
    short* Qh  = Wb + 4194304;                // [bh][s][64]
    short* Kb  = Qh + 4194304;                // [bh][s][64]
    short* Vh  = Kb + 4194304;                // [bh][s][64] natural
    short* Ctx = Vh + 4194304;                // [b*s][1024]
    short* Vt  = Xb;                          // [bh][64][s]

    cast_kernel<<<4096, 256, 0, stream>>>(X, Wq, Wk, Wv, Wo, Xb, Wb);

    // fused QKV projection: flat grid 24*32 = 768, swizzled in-kernel
    gemm_kernel<128, 0><<<768, 256, 0, stream>>>(
        Xb, Wb, bq, bk, bv, Qh, M_, 3 * D_, D_);

    vtrans_kernel<<<1024, 256, 0, stream>>>(Vh, Vt);

    attn_kernel<<<512, 256, 0, stream>>>(Qh, Kb, Vt, Ctx);

    // output projection: flat grid 16*32 = 512, swizzled in-kernel
    gemm_kernel<64, 2><<<512, 256, 0, stream>>>(
        Ctx, Wb + 3145728, bo, bo, bo, out, M_, D_, D_);
}

// Round 6
// 317.752 us; speedup vs baseline: 1.2586x; 1.1231x over previous
//
#include <hip/hip_runtime.h>

// ---------------------------------------------------------------------------
// MultiHeadAttention: B=2, S=2048, H=16, Dh=64, D=1024, causal mask, fp32 I/O.
// R6: 4-dispatch pipeline. QKV GEMM reads X fp32 directly (cvt at staging)
//     and writes V^T directly via transposed LDS epilogue (vtrans removed).
//     Weight cast is a tiny standalone kernel. Attn unchanged (R5).
// ---------------------------------------------------------------------------

#define B_   2
#define S_   2048
#define H_   16
#define DH_  64
#define D_   1024
#define M_   (B_ * S_)          // 4096 rows

typedef __attribute__((ext_vector_type(8))) short short8;
typedef __attribute__((ext_vector_type(4))) short short4_t;
typedef float v4f __attribute__((ext_vector_type(4)));

__device__ __forceinline__ short f2bf(float f) {
    union { float f; unsigned u; } v; v.f = f;
    unsigned r = v.u + 0x7fffu + ((v.u >> 16) & 1u);  // round-to-nearest-even
    return (short)(r >> 16);
}

// ---------------------------------------------------------------------------
// Kernel 1: cast Wq,Wk,Wv,Wo fp32 -> bf16 (weights only; 8 elems/thread).
// ---------------------------------------------------------------------------
__global__ __launch_bounds__(256) void castw_kernel(
    const float* __restrict__ Wq, const float* __restrict__ Wk,
    const float* __restrict__ Wv, const float* __restrict__ Wo,
    short* __restrict__ Wb)
{
    const int NW8 = (D_ * D_) / 8;      // 131,072
    int idx = blockIdx.x * 256 + threadIdx.x;   // 524,288 threads
    int sel = idx >> 17;
    int o = idx & (NW8 - 1);
    const float* src = (sel == 0) ? Wq : (sel == 1) ? Wk : (sel == 2) ? Wv : Wo;
    float4 f0 = ((const float4*)src)[o * 2];
    float4 f1 = ((const float4*)src)[o * 2 + 1];
    short8 s;
    s[0] = f2bf(f0.x); s[1] = f2bf(f0.y); s[2] = f2bf(f0.z); s[3] = f2bf(f0.w);
    s[4] = f2bf(f1.x); s[5] = f2bf(f1.y); s[6] = f2bf(f1.z); s[7] = f2bf(f1.w);
    *(short8*)(Wb + (size_t)sel * (D_ * D_) + (size_t)o * 8) = s;
}

// ---------------------------------------------------------------------------
// Kernel 2: C = A @ W(bf16,[N,K])^T + bias.  BM=128, BK=64, register-prefetch
// double buffering, XCD-aware flat-grid swizzle.
// MODE 0 (BN=128): A = X fp32 (cvt->bf16 at staging). Fused QKV, N=3072.
//   Epilogue via wave-private LDS: Q,K natural [bh][s][64]; V transposed
//   directly to Vt [bh][64][s].  All global stores 16B/lane.
// MODE 2 (BN=64):  A = Ctx bf16.  fp32 out [M,1024] (final projection).
// ---------------------------------------------------------------------------
template<int BN, int MODE>
__global__ __launch_bounds__(256) void gemm_kernel(
    const void* __restrict__ Av, const short* __restrict__ W,
    const float* __restrict__ bq, const float* __restrict__ bk,
    const float* __restrict__ bv, void* __restrict__ out,
    int M, int N, int K)
{
    __shared__ __align__(16) short smem[(128 + BN) * 72];
    short (*As)[72] = (short(*)[72])smem;
    short (*Bs)[72] = (short(*)[72])(smem + 128 * 72);

    const int t    = threadIdx.x;
    const int lane = t & 63;
    const int wave = t >> 6;

    // XCD-aware swizzle (flat grid): xcd = bid&7 owns by = 4*xcd..4*xcd+3
    const int bid = blockIdx.x;
    const int by  = ((bid & 7) << 2) + ((bid >> 3) & 3);
    const int bx  = bid >> 5;
    const int m0 = by * 128;
    const int n0 = bx * BN;

    const int wm = (wave >> 1) * 64;
    const int wn = (wave & 1) * (BN / 2);
    const int NJ = BN / 32;
    const int BIT = BN / 32;

    v4f acc[4][4] = {};

    const int lrow = t >> 3;           // 0..31
    const int lcol = (t & 7) * 8;

    const short* Wp = W + (size_t)(n0 + lrow) * K + lcol;
    uint4 pb[BIT];
    #pragma unroll
    for (int it = 0; it < BIT; ++it) pb[it] = *(const uint4*)(Wp + (size_t)it * 32 * K);

    // A prefetch registers (one variant used per MODE)
    const float* Apf = (const float*)Av + (size_t)(m0 + lrow) * K + lcol;
    const short* Apb = (const short*)Av + (size_t)(m0 + lrow) * K + lcol;
    float4 paf[4][2];
    uint4  pab[4];
    if constexpr (MODE == 0) {
        #pragma unroll
        for (int it = 0; it < 4; ++it) {
            paf[it][0] = *(const float4*)(Apf + (size_t)it * 32 * K);
            paf[it][1] = *(const float4*)(Apf + (size_t)it * 32 * K + 4);
        }
    } else {
        #pragma unroll
        for (int it = 0; it < 4; ++it) pab[it] = *(const uint4*)(Apb + (size_t)it * 32 * K);
    }

    for (int k0 = 0; k0 < K; k0 += 64) {
        __syncthreads();
        if constexpr (MODE == 0) {
            #pragma unroll
            for (int it = 0; it < 4; ++it) {
                short8 s8;
                s8[0] = f2bf(paf[it][0].x); s8[1] = f2bf(paf[it][0].y);
                s8[2] = f2bf(paf[it][0].z); s8[3] = f2bf(paf[it][0].w);
                s8[4] = f2bf(paf[it][1].x); s8[5] = f2bf(paf[it][1].y);
                s8[6] = f2bf(paf[it][1].z); s8[7] = f2bf(paf[it][1].w);
                *(short8*)&As[lrow + it * 32][lcol] = s8;
            }
        } else {
            #pragma unroll
            for (int it = 0; it < 4; ++it) *(uint4*)&As[lrow + it * 32][lcol] = pab[it];
        }
        #pragma unroll
        for (int it = 0; it < BIT; ++it) *(uint4*)&Bs[lrow + it * 32][lcol] = pb[it];

        if (k0 + 64 < K) {   // issue next tile's loads before the barrier
            if constexpr (MODE == 0) {
                #pragma unroll
                for (int it = 0; it < 4; ++it) {
                    paf[it][0] = *(const float4*)(Apf + (k0 + 64) + (size_t)it * 32 * K);
                    paf[it][1] = *(const float4*)(Apf + (k0 + 64) + (size_t)it * 32 * K + 4);
                }
            } else {
                #pragma unroll
                for (int it = 0; it < 4; ++it)
                    pab[it] = *(const uint4*)(Apb + (k0 + 64) + (size_t)it * 32 * K);
            }
            #pragma unroll
            for (int it = 0; it < BIT; ++it)
                pb[it] = *(const uint4*)(Wp + (k0 + 64) + (size_t)it * 32 * K);
        }
        __syncthreads();

        #pragma unroll
        for (int kk = 0; kk < 2; ++kk) {
            const int fr = lane & 15;
            const int fo = kk * 32 + (lane >> 4) * 8;
            short8 af[4], bf[4];
            #pragma unroll
            for (int i = 0; i < 4; ++i) af[i] = *(const short8*)&As[wm + i * 16 + fr][fo];
            #pragma unroll
            for (int j = 0; j < NJ; ++j) bf[j] = *(const short8*)&Bs[wn + j * 16 + fr][fo];
            #pragma unroll
            for (int i = 0; i < 4; ++i)
                #pragma unroll
                for (int j = 0; j < NJ; ++j)
                    acc[i][j] = __builtin_amdgcn_mfma_f32_16x16x32_bf16(af[i], bf[j], acc[i][j], 0, 0, 0);
        }
    }

    const int lm = lane & 15;
    const int lg = lane >> 4;
    const int sel = n0 >> 10;          // 0=Q 1=K 2=V (block-uniform, MODE 0)
    const float* bias = (MODE == 2) ? bq : (sel == 0) ? bq : (sel == 1) ? bk : bv;

    if constexpr (MODE == 2) {
        // fp32 direct: each quarter-wave covers full 64B lines per store.
        const int colb = n0 + wn + lm;
        const int rowb = m0 + wm + lg * 4;
        #pragma unroll
        for (int j = 0; j < NJ; ++j) {
            int col = colb + j * 16;
            float bv_ = bias[col];
            #pragma unroll
            for (int i = 0; i < 4; ++i)
                #pragma unroll
                for (int r = 0; r < 4; ++r)
                    ((float*)out)[(size_t)(rowb + i * 16 + r) * 1024 + col] = acc[i][j][r] + bv_;
        }
    } else {
        // bf16 via wave-private LDS region; 16B/lane wide stores.
        __syncthreads();                       // main-loop LDS reads all done
        short* Es = smem + wave * (64 * 72);
        const int cb = (n0 + wn) & 1023;       // 64-aligned feature base
        #pragma unroll
        for (int j = 0; j < 4; ++j) {
            float bv_ = bias[cb + j * 16 + lm];
            #pragma unroll
            for (int i = 0; i < 4; ++i)
                #pragma unroll
                for (int r = 0; r < 4; ++r) {
                    float vv = acc[i][j][r] + bv_;
                    if (sel < 2)    // Es[s_local][d]
                        Es[(i * 16 + lg * 4 + r) * 72 + j * 16 + lm] = f2bf(vv);
                    else            // V: Es[d][s_local]  (transposed)
                        Es[(j * 16 + lm) * 72 + i * 16 + lg * 4 + r] = f2bf(vv);
                }
        }
        __asm__ __volatile__("s_waitcnt lgkmcnt(0)" ::: "memory");
        short* outQKV = (short*)out;           // [Qh | Kb | Vt]
        const int rl = lane >> 3;              // 0..7
        const int c8 = (lane & 7) * 8;         // 0..56
        const int h  = cb >> 6;
        const int b  = (m0 + wm) >> 11;
        const int bh = (b << 4) + h;
        if (sel < 2) {
            #pragma unroll
            for (int it = 0; it < 8; ++it) {
                int row_l = it * 8 + rl;
                short8 vrow = *(const short8*)&Es[row_l * 72 + c8];
                int s = (m0 + wm + row_l) & 2047;
                *(short8*)(outQKV + (size_t)sel * 4194304 +
                           ((size_t)bh * S_ + s) * DH_ + c8) = vrow;
            }
        } else {
            const int s0 = (m0 + wm) & 2047;
            #pragma unroll
            for (int it = 0; it < 8; ++it) {
                int d_l = it * 8 + rl;
                short8 vrow = *(const short8*)&Es[d_l * 72 + c8];
                *(short8*)(outQKV + (size_t)2 * 4194304 +
                           ((size_t)bh << 17) + ((size_t)d_l << 11) + s0 + c8) = vrow;
            }
        }
    }
}

// ---------------------------------------------------------------------------
// Kernel 3: causal flash attention — barrier-free; paired long/short waves;
// flat grid of 512, swizzled so each XCD owns 4 bh.  (unchanged from R5)
// ---------------------------------------------------------------------------
__global__ __launch_bounds__(256, 2) void attn_kernel(
    const short* __restrict__ Q, const short* __restrict__ Kh,
    const short* __restrict__ Vt, short* __restrict__ ctx)
{
    __shared__ __align__(16) short Ps[4][2][16][72];

    const int t    = threadIdx.x;
    const int lane = t & 63;
    const int w    = t >> 6;
    const int bid  = blockIdx.x;                // 512 blocks
    const int bh   = ((bid & 7) << 2) + ((bid >> 3) & 3);
    const int qp   = bid >> 5;                  // 0..15
    const int p    = (w < 2) ? (qp * 2 + w) : (63 - (qp * 2 + (w - 2)));
    const int qr0  = p * 32;
    const int ktmax = (qr0 + 31) >> 6;

    const int lm = lane & 15;
    const int lg = lane >> 4;

    const short* Qb = Q  + ((size_t)bh * S_) * DH_;
    const short* Kb = Kh + ((size_t)bh * S_) * DH_;
    const short* Vb = Vt + ((size_t)bh << 17);

    short8 qf[2][2];
    #pragma unroll
    for (int t2 = 0; t2 < 2; ++t2)
        #pragma unroll
        for (int kk = 0; kk < 2; ++kk)
            qf[t2][kk] = *(const short8*)(Qb + (size_t)(qr0 + t2 * 16 + lm) * DH_ + kk * 32 + lg * 8);

    float m_i[2][4], l_i[2][4];
    v4f o[2][4] = {};
    #pragma unroll
    for (int t2 = 0; t2 < 2; ++t2)
        #pragma unroll
        for (int r = 0; r < 4; ++r) { m_i[t2][r] = -1e30f; l_i[t2][r] = 0.f; }

    for (int kt = 0; kt <= ktmax; ++kt) {
        const int kv0 = kt * 64;

        short8 kf[2][4], vf[2][4];
        #pragma unroll
        for (int kk = 0; kk < 2; ++kk)
            #pragma unroll
            for (int j = 0; j < 4; ++j) {
                kf[kk][j] = *(const short8*)(Kb + (size_t)(kv0 + j * 16 + lm) * DH_ + kk * 32 + lg * 8);
                vf[kk][j] = *(const short8*)(Vb + ((size_t)(j * 16 + lm) << 11) + kv0 + kk * 32 + lg * 8);
            }

        v4f sc[2][4] = {};
        #pragma unroll
        for (int kk = 0; kk < 2; ++kk)
            #pragma unroll
            for (int t2 = 0; t2 < 2; ++t2)
                #pragma unroll
                for (int j = 0; j < 4; ++j)
                    sc[t2][j] = __builtin_amdgcn_mfma_f32_16x16x32_bf16(qf[t2][kk], kf[kk][j], sc[t2][j], 0, 0, 0);

        #pragma unroll
        for (int t2 = 0; t2 < 2; ++t2) {
            float rm[4];
            const int rowb = qr0 + t2 * 16 + lg * 4;
            #pragma unroll
            for (int r = 0; r < 4; ++r) rm[r] = -1e30f;
            if (kt == ktmax) {
                #pragma unroll
                for (int j = 0; j < 4; ++j) {
                    int col = kv0 + j * 16 + lm;
                    #pragma unroll
                    for (int r = 0; r < 4; ++r) {
                        float v = sc[t2][j][r] * 0.125f;
                        if (col > rowb + r) v = -1e30f;
                        sc[t2][j][r] = v;
                        rm[r] = fmaxf(rm[r], v);
                    }
                }
            } else {
                #pragma unroll
                for (int j = 0; j < 4; ++j)
                    #pragma unroll
                    for (int r = 0; r < 4; ++r) {
                        float v = sc[t2][j][r] * 0.125f;
                        sc[t2][j][r] = v;
                        rm[r] = fmaxf(rm[r], v);
                    }
            }
            #pragma unroll
            for (int off = 1; off < 16; off <<= 1)
                #pragma unroll
                for (int r = 0; r < 4; ++r)
                    rm[r] = fmaxf(rm[r], __shfl_xor(rm[r], off, 64));

            float alpha[4], rs[4];
            #pragma unroll
            for (int r = 0; r < 4; ++r) {
                float mn = fmaxf(m_i[t2][r], rm[r]);
                alpha[r] = __expf(m_i[t2][r] - mn);
                m_i[t2][r] = mn;
                rs[r] = 0.f;
                #pragma unroll
                for (int j = 0; j < 4; ++j) {
                    float e = __expf(sc[t2][j][r] - mn);
                    sc[t2][j][r] = e;
                    rs[r] += e;
                }
            }
            #pragma unroll
            for (int off = 1; off < 16; off <<= 1)
                #pragma unroll
                for (int r = 0; r < 4; ++r)
                    rs[r] += __shfl_xor(rs[r], off, 64);
            #pragma unroll
            for (int r = 0; r < 4; ++r) l_i[t2][r] = l_i[t2][r] * alpha[r] + rs[r];
            #pragma unroll
            for (int j = 0; j < 4; ++j)
                #pragma unroll
                for (int r = 0; r < 4; ++r)
                    o[t2][j][r] *= alpha[r];

            #pragma unroll
            for (int j = 0; j < 4; ++j)
                #pragma unroll
                for (int r = 0; r < 4; ++r)
                    Ps[w][t2][lg * 4 + r][j * 16 + lm] = f2bf(sc[t2][j][r]);
        }

        __asm__ __volatile__("s_waitcnt lgkmcnt(0)" ::: "memory");

        #pragma unroll
        for (int kk = 0; kk < 2; ++kk)
            #pragma unroll
            for (int t2 = 0; t2 < 2; ++t2) {
                short8 pf = *(const short8*)&Ps[w][t2][lm][kk * 32 + lg * 8];
                #pragma unroll
                for (int j = 0; j < 4; ++j)
                    o[t2][j] = __builtin_amdgcn_mfma_f32_16x16x32_bf16(pf, vf[kk][j], o[t2][j], 0, 0, 0);
            }
    }

    const int b = bh >> 4, h = bh & 15;
    #pragma unroll
    for (int t2 = 0; t2 < 2; ++t2)
        #pragma unroll
        for (int r = 0; r < 4; ++r) {
            float inv = 1.f / l_i[t2][r];
            int s = qr0 + t2 * 16 + lg * 4 + r;
            size_t base = ((size_t)(b * S_ + s) << 10) + (h << 6);
            #pragma unroll
            for (int j = 0; j < 4; ++j)
                ctx[base + j * 16 + lm] = f2bf(o[t2][j][r] * inv);
        }
}

// ---------------------------------------------------------------------------
extern "C" void kernel_launch(void* const* d_in, const int* in_sizes, int n_in,
                              void* d_out, int out_size, void* d_ws, size_t ws_size,
                              hipStream_t stream) {
    const float* X  = (const float*)d_in[0];
    const float* Wq = (const float*)d_in[2];
    const float* bq = (const float*)d_in[3];
    const float* Wk = (const float*)d_in[4];
    const float* bk = (const float*)d_in[5];
    const float* Wv = (const float*)d_in[6];
    const float* bv = (const float*)d_in[7];
    const float* Wo = (const float*)d_in[8];
    const float* bo = (const float*)d_in[9];
    float* out = (float*)d_out;

    short* ws  = (short*)d_ws;
    short* Wb  = ws;                          // [Wq|Wk|Wv|Wo] bf16, 4x1,048,576
    short* Qh  = Wb + 4194304;                // [bh][s][64]
    short* Kb  = Qh + 4194304;                // [bh][s][64]
    short* Vt  = Kb + 4194304;                // [bh][64][s] (written by gemm)
    short* Ctx = Vt + 4194304;                // [b*s][1024]

    castw_kernel<<<2048, 256, 0, stream>>>(Wq, Wk, Wv, Wo, Wb);

    // fused QKV projection from fp32 X: flat grid 768, swizzled in-kernel
    gemm_kernel<128, 0><<<768, 256, 0, stream>>>(
        X, Wb, bq, bk, bv, Qh, M_, 3 * D_, D_);

    attn_kernel<<<512, 256, 0, stream>>>(Qh, Kb, Vt, Ctx);

    // output projection: flat grid 512, swizzled in-kernel
    gemm_kernel<64, 2><<<512, 256, 0, stream>>>(
        Ctx, Wb + 3145728, bo, bo, bo, out, M_, D_, D_);
}